// Round 9
// baseline (150.769 us; speedup 1.0000x reference)
//
#include <hip/hip_runtime.h>
#include <math.h>

#define H 512
#define W 512
#define NQ 11       // 0:s0 1-4:s1i..s4i 5-8:s1o..s4o 9:tex 10:shape
#define NBLK 8192   // 32 img * 256 row-pairs; one thread = 4-px strip of one row

// Flat max-TLP kernel: no LDS staging, no rolling window, no serial phases.
// 19 independent loads per thread issued up front; redundancy (3x row reads)
// served by L1/L2. XCD swizzle keeps adjacent rows on one XCD's L2.
__global__ __launch_bounds__(256) void radiomics_main(
    const float* __restrict__ inp, const float* __restrict__ outp,
    const float* __restrict__ mask, double* __restrict__ partials)
{
    const int tid  = threadIdx.x;
    const int lane = tid & 63;
    const int wib  = tid >> 6;
    const int blk  = blockIdx.x;
    // swizzle: blk%8 = assumed XCD; each XCD gets a contiguous 64-row slab
    // per image (performance heuristic only — correctness is mapping-free).
    const int slab = blk & 7;
    const int idx  = blk >> 3;            // 0..1023
    const int img  = idx >> 5;            // 0..31
    const int rp   = idx & 31;            // row-pair within slab
    const int r    = slab * 64 + rp * 2 + (tid >> 7);  // this thread's row
    const int x0   = (tid & 127) * 4;                  // 4-px strip start

    const size_t off = (size_t)img * H * W;
    const float* Ab = inp  + off;
    const float* Bb = outp + off;

    // ---- 19 independent loads: 3 rows x 2 img x (float4 + 2 halos) + mask ----
    float a[3][6], b[3][6];
    #pragma unroll
    for (int dy = 0; dy < 3; dy++) {
        const int y = r - 1 + dy;
        const bool yok = (y >= 0) && (y < H);
        const float* pa = Ab + (size_t)(yok ? y : 0) * W + x0;
        const float* pb = Bb + (size_t)(yok ? y : 0) * W + x0;
        float4 va = yok ? *(const float4*)pa : make_float4(0.f,0.f,0.f,0.f);
        float4 vb = yok ? *(const float4*)pb : make_float4(0.f,0.f,0.f,0.f);
        float la = (yok && x0 > 0)     ? pa[-1] : 0.0f;
        float lb = (yok && x0 > 0)     ? pb[-1] : 0.0f;
        float ra = (yok && x0 + 4 < W) ? pa[4]  : 0.0f;
        float rb = (yok && x0 + 4 < W) ? pb[4]  : 0.0f;
        a[dy][0]=la; a[dy][1]=va.x; a[dy][2]=va.y; a[dy][3]=va.z; a[dy][4]=va.w; a[dy][5]=ra;
        b[dy][0]=lb; b[dy][1]=vb.x; b[dy][2]=vb.y; b[dy][3]=vb.z; b[dy][4]=vb.w; b[dy][5]=rb;
    }
    float4 m4 = *(const float4*)(mask + off + (size_t)r * W + x0);
    const float mk[4] = { m4.x, m4.y, m4.z, m4.w };

    const float inv9 = 1.0f / 9.0f;
    float acc[NQ];
    #pragma unroll
    for (int q = 0; q < NQ; q++) acc[q] = 0.0f;

    // ---- image 0: local variance + laplacian + input moments ----
    float c1[6], c2[6], tvI[4], lpI[4];
    #pragma unroll
    for (int k = 0; k < 6; k++) {
        c1[k] = a[0][k] + a[1][k] + a[2][k];
        c2[k] = fmaf(a[0][k], a[0][k], fmaf(a[1][k], a[1][k], a[2][k] * a[2][k]));
    }
    #pragma unroll
    for (int j = 0; j < 4; j++) {
        float s1 = c1[j] + c1[j+1] + c1[j+2];
        float s2 = c2[j] + c2[j+1] + c2[j+2];
        float mn = s1 * inv9;
        tvI[j] = fmaf(-mn, mn, s2 * inv9);
        lpI[j] = a[0][j+1] + a[2][j+1] + a[1][j] + a[1][j+2] - 4.0f * a[1][j+1];
        float m = mk[j];
        acc[0] += m;
        float x = a[1][j+1];
        float t = x * m; acc[1] += t; t *= x; acc[2] += t; t *= x; acc[3] += t; t *= x; acc[4] += t;
    }
    // ---- image 1: diffs + output moments ----
    #pragma unroll
    for (int k = 0; k < 6; k++) {
        c1[k] = b[0][k] + b[1][k] + b[2][k];
        c2[k] = fmaf(b[0][k], b[0][k], fmaf(b[1][k], b[1][k], b[2][k] * b[2][k]));
    }
    #pragma unroll
    for (int j = 0; j < 4; j++) {
        float s1 = c1[j] + c1[j+1] + c1[j+2];
        float s2 = c2[j] + c2[j+1] + c2[j+2];
        float mn = s1 * inv9;
        float tv = fmaf(-mn, mn, s2 * inv9);
        float lp = b[0][j+1] + b[2][j+1] + b[1][j] + b[1][j+2] - 4.0f * b[1][j+1];
        float m = mk[j];
        acc[9]  += fabsf(tv * m - tvI[j] * m);
        acc[10] += fabsf(lp * m - lpI[j] * m);
        float x = b[1][j+1];
        float t = x * m; acc[5] += t; t *= x; acc[6] += t; t *= x; acc[7] += t; t *= x; acc[8] += t;
    }

    // ---- wave shuffle-reduce, tiny LDS block-reduce, fp64 per-block partial ----
    #pragma unroll
    for (int q = 0; q < NQ; q++) {
        float v = acc[q];
        #pragma unroll
        for (int o = 32; o > 0; o >>= 1) v += __shfl_down(v, o);
        acc[q] = v;
    }
    __shared__ float red[4][NQ];
    if (lane == 0) {
        #pragma unroll
        for (int q = 0; q < NQ; q++) red[wib][q] = acc[q];
    }
    __syncthreads();
    if (tid < NQ) {
        double s = (double)red[0][tid] + (double)red[1][tid]
                 + (double)red[2][tid] + (double)red[3][tid];
        partials[(size_t)blk * NQ + tid] = s;
    }
}

__global__ __launch_bounds__(1024) void radiomics_final(
    const double* __restrict__ partials, int nblk, float* __restrict__ out4, double inv_n)
{
    const int tid = threadIdx.x;
    const int lane = tid & 63;
    const int w = tid >> 6;                 // 16 waves
    double q[NQ];
    #pragma unroll
    for (int k = 0; k < NQ; k++) q[k] = 0.0;
    for (int i = tid; i < nblk; i += 1024) {
        #pragma unroll
        for (int k = 0; k < NQ; k++) q[k] += partials[(size_t)i * NQ + k];
    }
    #pragma unroll
    for (int k = 0; k < NQ; k++) {
        #pragma unroll
        for (int o = 32; o > 0; o >>= 1) q[k] += __shfl_down(q[k], o);
    }
    __shared__ double red[16][NQ];
    if (lane == 0) {
        #pragma unroll
        for (int k = 0; k < NQ; k++) red[w][k] = q[k];
    }
    __syncthreads();
    if (tid == 0) {
        double s[NQ];
        #pragma unroll
        for (int k = 0; k < NQ; k++) {
            double t = 0.0;
            #pragma unroll
            for (int ww = 0; ww < 16; ww++) t += red[ww][k];
            s[k] = t;
        }
        const double EPS = 1e-8;
        double S0 = s[0];
        double ms = S0 + EPS;
        double im = s[1] / ms, om = s[5] / ms;
        double im2 = im * im, im3 = im2 * im, im4 = im2 * im2;
        double om2 = om * om, om3 = om2 * om, om4 = om2 * om2;
        double di2 = s[2] - 2.0*im*s[1] + im2*S0;
        double do2 = s[6] - 2.0*om*s[5] + om2*S0;
        double iv = di2 / ms, ov = do2 / ms;
        double di3 = s[3] - 3.0*im*s[2] + 3.0*im2*s[1] - im3*S0;
        double do3 = s[7] - 3.0*om*s[6] + 3.0*om2*s[5] - om3*S0;
        double isk = di3 / (ms * (iv * sqrt(iv) + EPS));
        double osk = do3 / (ms * (ov * sqrt(ov) + EPS));
        double di4 = s[4] - 4.0*im*s[3] + 6.0*im2*s[2] - 4.0*im3*s[1] + im4*S0;
        double do4 = s[8] - 4.0*om*s[7] + 6.0*om2*s[6] - 4.0*om3*s[5] + om4*S0;
        double iku = di4 / (ms * (iv * iv + EPS));
        double oku = do4 / (ms * (ov * ov + EPS));
        double intensity = (im-om)*(im-om) + (iv-ov)*(iv-ov)
                         + (isk-osk)*(isk-osk) + (iku-oku)*(iku-oku);
        double texture = s[9]  * inv_n;
        double shape   = s[10] * inv_n;
        // TEXTURE_W=1.0, SHAPE_W=0.5, INTENSITY_W=1.0
        double total = intensity + texture + 0.5 * shape;
        out4[0] = (float)intensity;
        out4[1] = (float)texture;
        out4[2] = (float)shape;
        out4[3] = (float)total;
    }
}

extern "C" void kernel_launch(void* const* d_in, const int* in_sizes, int n_in,
                              void* d_out, int out_size, void* d_ws, size_t ws_size,
                              hipStream_t stream) {
    const float* inp  = (const float*)d_in[0];
    const float* outp = (const float*)d_in[1];
    const float* mask = (const float*)d_in[2];
    const int total = in_sizes[0];             // 32*1*512*512
    double* partials = (double*)d_ws;          // NBLK*NQ doubles, fully overwritten

    radiomics_main<<<NBLK, 256, 0, stream>>>(inp, outp, mask, partials);
    const double inv_n = 1.0 / (double)total;
    radiomics_final<<<1, 1024, 0, stream>>>(partials, NBLK, (float*)d_out, inv_n);
}